// Round 6
// baseline (1876.400 us; speedup 1.0000x reference)
//
#include <hip/hip_runtime.h>
#include <math.h>

#define B_    16
#define BCH   4            // batch chunk for conv1/conv2
#define T_    4096
#define C_    256
#define CIN1  80
#define EMB   128
#define TP    341
#define NPOS  (B_*TP)      // 5456
#define NQ_   8
#define KCB   256
#define BN_EPS 1e-5

// ---------------- prep: f64 transposes + BN fold ----------------
__global__ __launch_bounds__(256) void prep_f64(
    const float* __restrict__ w1, const float* __restrict__ w2,
    const float* __restrict__ wd,
    const float* __restrict__ b1, const float* __restrict__ g1,
    const float* __restrict__ be1, const float* __restrict__ m1,
    const float* __restrict__ v1,
    const float* __restrict__ b2, const float* __restrict__ g2,
    const float* __restrict__ be2, const float* __restrict__ m2,
    const float* __restrict__ v2,
    const float* __restrict__ wp, const float* __restrict__ bp,
    double* __restrict__ w1t, double* __restrict__ w2t, double* __restrict__ wdt,
    double* __restrict__ a1, double* __restrict__ bt1,
    double* __restrict__ a2, double* __restrict__ bt2,
    double* __restrict__ wpd, double* __restrict__ bpd)
{
    int j = blockIdx.x * 256 + threadIdx.x;
    if (j < 256*24*128) wdt[j] = (double)wd[(size_t)(j & 127) * 6144 + (j >> 7)];
    if (j < 256*5*256)  w2t[j] = (double)w2[(size_t)(j & 255) * 1280 + (j >> 8)];
    if (j < 80*5*256)   w1t[j] = (double)w1[(size_t)(j & 255) * 400 + (j >> 8)];
    if (j < 16*128)     wpd[j] = (double)wp[j];
    if (j < 16)         bpd[j] = (double)bp[j];
    if (j < 256) {
        double inv1 = 1.0 / sqrt((double)v1[j] + BN_EPS);
        double s1 = (double)g1[j] * inv1;
        a1[j]  = s1;
        bt1[j] = ((double)b1[j] - (double)m1[j]) * s1 + (double)be1[j];
        double inv2 = 1.0 / sqrt((double)v2[j] + BN_EPS);
        double s2 = (double)g2[j] * inv2;
        a2[j]  = s2;
        bt2[j] = ((double)b2[j] - (double)m2[j]) * s2 + (double)be2[j];
    }
}

// bank swizzle on 16B granularity (used by conv5 only)
__device__ __forceinline__ int swz_pair(int col) {        // col even, 16B unit
    int bw = col >> 1;
    return ((bw ^ ((bw >> 3) & 7)) << 1);
}
__device__ __forceinline__ int swz_scalar(int col) {      // any col (8B unit)
    int bw = col >> 1;
    return (((bw ^ ((bw >> 3) & 7)) << 1) | (col & 1));
}

// ---------------- f64 conv(k=5,pad=2) + BN + ReLU ----------------
// block: 64 co x 128 t for one (local) batch. 256 thr: 16 tcol (8 t) x 16 trow (4 co)
template<int CIN, typename Tin>
__global__ __launch_bounds__(256) void conv5_bn_relu_f64(
    const Tin* __restrict__ in,       // [BCH][CIN][T]
    const double* __restrict__ wt,    // [(ci*5+k)][256]
    const double* __restrict__ alpha, const double* __restrict__ beta,
    double* __restrict__ out)         // [BCH][256][T]
{
    const int b   = blockIdx.z;
    const int co0 = blockIdx.y * 64;
    const int t0  = blockIdx.x * 128;
    const int tid = threadIdx.x;
    const int tcol = tid & 15;
    const int trow = tid >> 4;

    __shared__ double xs[8][136];     // 8704 B (132 used, swizzled)
    __shared__ double wsh[40][64];    // 20480 B

    double acc[4][8];
    #pragma unroll
    for (int i = 0; i < 4; ++i)
        #pragma unroll
        for (int j = 0; j < 8; ++j) acc[i][j] = 0.0;

    for (int c0 = 0; c0 < CIN; c0 += 8) {
        for (int i = tid; i < 8 * 132; i += 256) {
            int ci = i / 132, col = i % 132;
            int t = t0 - 2 + col;
            double v = 0.0;
            if (t >= 0 && t < T_) v = (double)in[((size_t)(b * CIN + c0 + ci)) * T_ + t];
            xs[ci][swz_scalar(col)] = v;
        }
        for (int i = tid; i < 40 * 64; i += 256) {
            int r = i >> 6, co = i & 63;
            wsh[r][co] = wt[(size_t)(c0 * 5 + r) * 256 + co0 + co];
        }
        __syncthreads();

        #pragma unroll
        for (int ci = 0; ci < 8; ++ci) {
            double xv[12];
            #pragma unroll
            for (int m = 0; m < 6; ++m) {
                double2 v = *(const double2*)&xs[ci][swz_pair(tcol * 8 + 2 * m)];
                xv[2 * m] = v.x; xv[2 * m + 1] = v.y;
            }
            #pragma unroll
            for (int k = 0; k < 5; ++k) {
                double w0 = wsh[ci * 5 + k][trow * 4 + 0];
                double w1v = wsh[ci * 5 + k][trow * 4 + 1];
                double w2v = wsh[ci * 5 + k][trow * 4 + 2];
                double w3v = wsh[ci * 5 + k][trow * 4 + 3];
                #pragma unroll
                for (int j = 0; j < 8; ++j) {
                    double xq = xv[j + k];
                    acc[0][j] = fma(w0, xq, acc[0][j]);
                    acc[1][j] = fma(w1v, xq, acc[1][j]);
                    acc[2][j] = fma(w2v, xq, acc[2][j]);
                    acc[3][j] = fma(w3v, xq, acc[3][j]);
                }
            }
        }
        __syncthreads();
    }

    const int cobase = co0 + trow * 4;
    const int tg = t0 + tcol * 8;
    #pragma unroll
    for (int i = 0; i < 4; ++i) {
        double a = alpha[cobase + i], bt = beta[cobase + i];
        size_t base = ((size_t)(b * C_ + cobase + i)) * T_ + tg;
        #pragma unroll
        for (int j = 0; j < 8; ++j) {
            double y = fma(acc[i][j], a, bt);
            out[base + j] = y > 0.0 ? y : 0.0;
        }
    }
}

// ---------------- f64 downsample conv v6: k=24, stride=12, pad=6 ----------------
// block: ALL 128 co x 64 tp. 256 thr: tcol=tid&15 (4 tp: tcol+16j), crow=tid>>4
// (8 co: crow*8+i). x staged kpos-major (xs2[ci][kpos][tp]) -> every compute
// read is stride-1 across lanes (conflict-free) with compile-time offsets.
// ci split nsplit ways across grid.z. Writes f64 partials.
__global__ __launch_bounds__(256) void convd_f64_v6(
    const double* __restrict__ x2,    // [nb][256][T]
    const double* __restrict__ wdt,   // [(ci*24+k)][128]
    double* __restrict__ parts,       // [nsplit][nb][128][341]
    int nb, int nsplit, int cis)
{
    const int bz  = blockIdx.z;
    const int s   = bz % nsplit;
    const int b   = bz / nsplit;
    const int tp0 = blockIdx.x * 64;
    const int tid = threadIdx.x;
    const int tcol = tid & 15;
    const int crow = tid >> 4;

    __shared__ double xs2[2][24][66]; // 25344 B, kpos-major
    __shared__ double wsh[48][128];   // 49152 B

    double acc[8][4];
    #pragma unroll
    for (int i = 0; i < 8; ++i)
        #pragma unroll
        for (int j = 0; j < 4; ++j) acc[i][j] = 0.0;

    const int tbase = tp0 * 12 - 6;
    const int ci_begin = s * cis;

    for (int c0 = ci_begin; c0 < ci_begin + cis; c0 += 2) {
        // stage x: span = 63*12+24 = 780 per ci; each element -> its <=2 windows
        for (int i = tid; i < 2 * 780; i += 256) {
            int ci = i / 780, c = i % 780;
            int t = tbase + c;
            double v = (t >= 0 && t < T_)
                ? x2[((size_t)(b * 256 + c0 + ci)) * T_ + t] : 0.0;
            int tp = c / 12, kp = c % 12;
            xs2[ci][kp][tp] = v;
            if (tp >= 1) xs2[ci][kp + 12][tp - 1] = v;
        }
        // stage w: 48 rows x 128 co
        for (int i = tid; i < 48 * 128; i += 256) {
            int r = i >> 7, c = i & 127;
            wsh[r][c] = wdt[(size_t)(c0 * 24 + r) * 128 + c];
        }
        __syncthreads();

        const double* xb = &xs2[0][0][0] + tcol;
        const double* wb = &wsh[0][0] + crow * 8;
        #pragma unroll
        for (int ci = 0; ci < 2; ++ci) {
            #pragma unroll
            for (int k = 0; k < 24; ++k) {
                double wv[8], xv[4];
                #pragma unroll
                for (int i = 0; i < 8; ++i) wv[i] = wb[(ci * 24 + k) * 128 + i];
                #pragma unroll
                for (int j = 0; j < 4; ++j) xv[j] = xb[(ci * 24 + k) * 66 + 16 * j];
                #pragma unroll
                for (int i = 0; i < 8; ++i)
                    #pragma unroll
                    for (int j = 0; j < 4; ++j)
                        acc[i][j] = fma(wv[i], xv[j], acc[i][j]);
            }
        }
        __syncthreads();
    }

    #pragma unroll
    for (int i = 0; i < 8; ++i) {
        int co = crow * 8 + i;
        #pragma unroll
        for (int j = 0; j < 4; ++j) {
            int tp = tp0 + tcol + 16 * j;
            if (tp < TP)
                parts[(((size_t)s * nb + b) * EMB + co) * TP + tp] = acc[i][j];
        }
    }
}

// ---------------- combine partials + bias -> ed (f64) + e_out (f32) ----------------
__global__ __launch_bounds__(256) void convd_combine(
    const double* __restrict__ parts, // [nsplit][nb][128][341]
    const float* __restrict__ bd,
    double* __restrict__ ed,          // [16][128][341] (absolute b)
    float* __restrict__ e_out,        // [16][128][341]
    int nb, int b_off, int nsplit)
{
    int idx = blockIdx.x * 256 + threadIdx.x;
    int total = nb * EMB * TP;
    if (idx >= total) return;
    int b_local = idx / (EMB * TP);
    int rem = idx % (EMB * TP);
    int co = rem / TP;
    size_t stride = (size_t)nb * EMB * TP;
    double y = 0.0;
    for (int s = 0; s < nsplit; ++s)     // ascending s: deterministic
        y += parts[(size_t)s * stride + idx];
    y += (double)bd[co];
    size_t o = (size_t)(b_off + b_local) * EMB * TP + rem;
    ed[o] = y;
    e_out[o] = (float)y;
}

// ---------------- f64 1x1 projection ----------------
__global__ __launch_bounds__(128) void zproj_f64(
    const double* __restrict__ ed,    // [B][128][341]
    const double* __restrict__ wpd,   // [16][128]
    const double* __restrict__ bpd,   // [16]
    double* __restrict__ z)           // [B][341][16]
{
    const int b = blockIdx.y;
    const int t = blockIdx.x * 128 + threadIdx.x;
    __shared__ double wps[16][128];
    for (int i = threadIdx.x; i < 16 * 128; i += 128)
        wps[i >> 7][i & 127] = wpd[i];
    __syncthreads();
    if (t >= TP) return;
    double acc[16];
    #pragma unroll
    for (int v = 0; v < 16; ++v) acc[v] = bpd[v];
    for (int co = 0; co < 128; ++co) {
        double x = ed[((size_t)(b * EMB + co)) * TP + t];
        #pragma unroll
        for (int v = 0; v < 16; ++v) acc[v] = fma(x, wps[v][co], acc[v]);
    }
    #pragma unroll
    for (int v = 0; v < 16; ++v)
        z[((size_t)(b * TP + t)) * 16 + v] = acc[v];
}

// ---------------- RVQ: f64 distances, wave-shuffle argmin ----------------
__global__ __launch_bounds__(256) void rvq_f64_v2(
    const double* __restrict__ z,     // [NPOS][16]
    const float* __restrict__ cb,     // [8][256][16]
    float* __restrict__ out_idx)      // [8][NPOS] as float
{
    const int pos = blockIdx.x;
    const int tid = threadIdx.x;
    const int lane = tid & 63;
    const int wv = tid >> 6;

    __shared__ double r[16];
    __shared__ double wd_s[4];
    __shared__ int wi_s[4];
    __shared__ int best_s;

    if (tid < 16) r[tid] = z[(size_t)pos * 16 + tid];
    __syncthreads();

    for (int q = 0; q < NQ_; ++q) {
        const float* c = cb + ((size_t)(q * KCB) + tid) * 16;
        double d = 0.0;
        #pragma unroll
        for (int i = 0; i < 16; ++i) {
            double diff = r[i] - (double)c[i];
            d = fma(diff, diff, d);
        }
        int idx = tid;
        #pragma unroll
        for (int sft = 32; sft > 0; sft >>= 1) {
            double d2 = __shfl_down(d, sft, 64);
            int i2 = __shfl_down(idx, sft, 64);
            if (d2 < d || (d2 == d && i2 < idx)) { d = d2; idx = i2; }
        }
        if (lane == 0) { wd_s[wv] = d; wi_s[wv] = idx; }
        __syncthreads();
        if (tid == 0) {
            double bd_ = wd_s[0]; int bi = wi_s[0];
            #pragma unroll
            for (int w = 1; w < 4; ++w) {
                if (wd_s[w] < bd_ || (wd_s[w] == bd_ && wi_s[w] < bi)) {
                    bd_ = wd_s[w]; bi = wi_s[w];
                }
            }
            best_s = bi;
            out_idx[(size_t)q * NPOS + pos] = (float)bi;
        }
        __syncthreads();
        int best = best_s;
        if (tid < 16)
            r[tid] = r[tid] - (double)cb[((size_t)(q * KCB) + best) * 16 + tid];
        __syncthreads();
    }
}

// ---------------- host launcher ----------------
extern "C" void kernel_launch(void* const* d_in, const int* in_sizes, int n_in,
                              void* d_out, int out_size, void* d_ws, size_t ws_size,
                              hipStream_t stream) {
    const float* mel = (const float*)d_in[0];
    const float* w1  = (const float*)d_in[1];
    const float* b1  = (const float*)d_in[2];
    const float* g1  = (const float*)d_in[3];
    const float* be1 = (const float*)d_in[4];
    const float* m1  = (const float*)d_in[5];
    const float* v1  = (const float*)d_in[6];
    const float* w2  = (const float*)d_in[7];
    const float* b2  = (const float*)d_in[8];
    const float* g2  = (const float*)d_in[9];
    const float* be2 = (const float*)d_in[10];
    const float* m2  = (const float*)d_in[11];
    const float* v2  = (const float*)d_in[12];
    const float* wd  = (const float*)d_in[13];
    const float* bd  = (const float*)d_in[14];
    const float* wp  = (const float*)d_in[15];
    const float* bp  = (const float*)d_in[16];
    const float* cb  = (const float*)d_in[17];

    const int nb = 8;                  // batches per convd group
    const int ngrp = B_ / nb;          // 2

    const size_t x1_bytes    = (size_t)BCH * C_ * T_ * 8;          // 33.55 MB
    const size_t x2_bytes    = (size_t)nb * C_ * T_ * 8;           // 67.11 MB
    const size_t fixed_bytes = x2_bytes + (size_t)80*5*256*8 + (size_t)256*5*256*8
                             + (size_t)256*24*128*8 + 4*2048 + 16384 + 256
                             + (size_t)16 * EMB * TP * 8           // ed
                             + (size_t)16 * TP * 16 * 8            // zd
                             + 16384;                              // align slack
    auto parts_bytes = [&](int ns) -> size_t {
        return (size_t)ns * nb * EMB * TP * 8;
    };
    // parts aliased over x1 (x1 is dead by the time convd runs in each group)
    auto need = [&](int ns) -> size_t {
        size_t shared = x1_bytes > parts_bytes(ns) ? x1_bytes : parts_bytes(ns);
        return shared + fixed_bytes;
    };
    int nsplit = (ws_size >= need(16)) ? 16 : 8;
    const int cis = 256 / nsplit;
    const size_t shared_bytes =
        x1_bytes > parts_bytes(nsplit) ? x1_bytes : parts_bytes(nsplit);

    char* ws = (char*)d_ws;
    size_t off = 0;
    auto alloc = [&](size_t bytes) -> char* {
        char* p = ws + off;
        off = (off + bytes + 255) & ~(size_t)255;
        return p;
    };
    char* shared = alloc(shared_bytes);
    double* x1d  = (double*)shared;
    double* parts= (double*)shared;
    double* x2d  = (double*)alloc(x2_bytes);
    double* w1td = (double*)alloc((size_t)80*5*256*8);
    double* w2td = (double*)alloc((size_t)256*5*256*8);
    double* wdtd = (double*)alloc((size_t)256*24*128*8);
    double* a1d  = (double*)alloc(2048);
    double* bt1d = (double*)alloc(2048);
    double* a2d  = (double*)alloc(2048);
    double* bt2d = (double*)alloc(2048);
    double* wpd  = (double*)alloc(16*128*8);
    double* bpd  = (double*)alloc(16*8);
    double* ed   = (double*)alloc((size_t)16 * EMB * TP * 8);
    double* zd   = (double*)alloc((size_t)16 * TP * 16 * 8);

    float* e_out   = (float*)d_out;                          // [16][128][341]
    float* idx_out = (float*)d_out + (size_t)B_ * EMB * TP;  // [8][16][341]

    prep_f64<<<3072, 256, 0, stream>>>(w1, w2, wd, b1, g1, be1, m1, v1,
                                       b2, g2, be2, m2, v2, wp, bp,
                                       w1td, w2td, wdtd, a1d, bt1d, a2d, bt2d,
                                       wpd, bpd);

    const int comb_blocks = (nb * EMB * TP + 255) / 256;
    for (int g = 0; g < ngrp; ++g) {
        for (int ch = 0; ch < nb / BCH; ++ch) {
            int ch_abs = g * (nb / BCH) + ch;
            const float* mel_c = mel + (size_t)ch_abs * BCH * CIN1 * T_;
            conv5_bn_relu_f64<CIN1, float><<<dim3(32, 4, BCH), 256, 0, stream>>>(
                mel_c, w1td, a1d, bt1d, x1d);
            conv5_bn_relu_f64<C_, double><<<dim3(32, 4, BCH), 256, 0, stream>>>(
                x1d, w2td, a2d, bt2d, x2d + (size_t)ch * BCH * C_ * T_);
        }
        // x1 dead from here until next group's conv1 -> parts may reuse it
        convd_f64_v6<<<dim3(6, 1, nb * nsplit), 256, 0, stream>>>(
            x2d, wdtd, parts, nb, nsplit, cis);
        convd_combine<<<comb_blocks, 256, 0, stream>>>(parts, bd, ed, e_out,
                                                       nb, g * nb, nsplit);
    }
    zproj_f64<<<dim3(3, 16), 128, 0, stream>>>(ed, wpd, bpd, zd);
    rvq_f64_v2<<<NPOS, 256, 0, stream>>>(zd, cb, idx_out);
}